// Round 20
// baseline (210.238 us; speedup 1.0000x reference)
//
#include <hip/hip_runtime.h>
#include <hip/hip_fp16.h>

#define N_NODES 4096
#define DIMS 128

typedef __attribute__((ext_vector_type(8))) short short8;
typedef __attribute__((ext_vector_type(4))) float f32x4;

static constexpr float BIGF = 1e9f;
static constexpr float EPSF = 1e-12f;
static constexpr unsigned long long KEY_INF = ~0ull;
static constexpr unsigned U32_INF = 0xFFFFFFFFu;

// ---------------- helpers ----------------

__device__ inline unsigned short f32_to_bf16(float f) {
    unsigned u = __float_as_uint(f);
    unsigned r = (u + 0x7FFFu + ((u >> 16) & 1u)) >> 16;   // RNE
    return (unsigned short)r;
}

// D stores fp16(d^2); deaths decode with sqrt at emit time.
__device__ inline float half_bits_to_death(unsigned short b) {
    __half h;
    __builtin_memcpy(&h, &b, 2);
    return sqrtf(__half2float(h));
}

__device__ inline unsigned u32min(unsigned a, unsigned b) { return a < b ? a : b; }

__device__ inline unsigned long long u64min(unsigned long long a, unsigned long long b) {
    return a < b ? a : b;
}

__device__ inline unsigned long long shfl_xor_u64(unsigned long long v, int m) {
    int lo = __shfl_xor((int)(unsigned)(v & 0xFFFFFFFFull), m);
    int hi = __shfl_xor((int)(unsigned)(v >> 32), m);
    return ((unsigned long long)(unsigned)hi << 32) | (unsigned)lo;
}

__device__ inline unsigned wave_min_u32(unsigned v) {
    #pragma unroll
    for (int s = 32; s; s >>= 1) v = u32min(v, (unsigned)__shfl_xor((int)v, s));
    return v;
}

__device__ inline float block_reduce_sum_256(float v) {
    __shared__ float s[4];
    __syncthreads();
    #pragma unroll
    for (int off = 32; off; off >>= 1) v += __shfl_xor(v, off);
    if ((threadIdx.x & 63) == 0) s[threadIdx.x >> 6] = v;
    __syncthreads();
    return s[0] + s[1] + s[2] + s[3];
}

// ---------------- prep: bf16 convert, norms, repr partials, init ----------------
// grid 512 x 256
__global__ __launch_bounds__(256) void prep_kernel(const float* __restrict__ S,
                                                   const float* __restrict__ T,
                                                   unsigned short* __restrict__ X16s,
                                                   unsigned short* __restrict__ X16t,
                                                   float* __restrict__ sqs,
                                                   float* __restrict__ sqt,
                                                   float* __restrict__ partials,
                                                   unsigned short* __restrict__ comp0,
                                                   unsigned long long* __restrict__ best_row,
                                                   unsigned* __restrict__ cnt,
                                                   unsigned* __restrict__ done,
                                                   unsigned* __restrict__ sctl) {
    const int t = threadIdx.x;
    const int gid = blockIdx.x * 256 + t;
    if (gid < 2 * N_NODES) {
        comp0[gid] = (unsigned short)(gid & (N_NODES - 1));
        best_row[gid] = KEY_INF;               // dist epilogue atomicMins real edges in
    }
    if (gid < 2) { cnt[gid] = 0; done[gid] = 0; }
    if (gid == 0) sctl[0] = 0;

    const int wave = t >> 6, lane = t & 63;
    const int row = blockIdx.x * 8 + wave * 2 + (lane >> 5);
    const int c4 = (lane & 31) * 4;
    const size_t off = (size_t)row * DIMS + c4;
    float4 a = *(const float4*)&S[off];
    float4 b = *(const float4*)&T[off];
    float sa = a.x * a.x + a.y * a.y + a.z * a.z + a.w * a.w;
    float sb = b.x * b.x + b.y * b.y + b.z * b.z + b.w * b.w;
    #pragma unroll
    for (int m = 16; m; m >>= 1) { sa += __shfl_xor(sa, m); sb += __shfl_xor(sb, m); }
    if ((lane & 31) == 0) { sqs[row] = sa; sqt[row] = sb; }
    ushort4 oa, ob;
    oa.x = f32_to_bf16(a.x); oa.y = f32_to_bf16(a.y);
    oa.z = f32_to_bf16(a.z); oa.w = f32_to_bf16(a.w);
    ob.x = f32_to_bf16(b.x); ob.y = f32_to_bf16(b.y);
    ob.z = f32_to_bf16(b.z); ob.w = f32_to_bf16(b.w);
    *(ushort4*)&X16s[off] = oa;
    *(ushort4*)&X16t[off] = ob;
    float dx = a.x - b.x, dy = a.y - b.y, dz = a.z - b.z, dw = a.w - b.w;
    float rs = block_reduce_sum_256(dx * dx + dy * dy + dz * dz + dw * dw);
    if (t == 0) partials[blockIdx.x] = rs;
}

// ---------------- distance matrix: triangular MFMA, rowtile mins --------------
// K staged in two 64-dim chunks (26.6 KB LDS -> 6 blocks/CU); D stores fp16(d^2).
__global__ __launch_bounds__(256) void dist_kernel(const unsigned short* __restrict__ X16s,
                                                   const unsigned short* __restrict__ X16t,
                                                   const float* __restrict__ sqs,
                                                   const float* __restrict__ sqt,
                                                   __half* __restrict__ Ds,
                                                   __half* __restrict__ Dt,
                                                   unsigned long long* __restrict__ best_row,
                                                   unsigned* __restrict__ rowtile) {
    const int bi = blockIdx.y * 64;
    const int bj = blockIdx.x * 64;
    if (bj < bi) return;
    const int m = blockIdx.z;
    const unsigned short* __restrict__ X16 = m ? X16t : X16s;
    const float* __restrict__ sq = m ? sqt : sqs;
    unsigned short* __restrict__ D = (unsigned short*)(m ? Dt : Ds);
    unsigned long long* br = best_row + m * N_NODES;
    unsigned* rt = rowtile + (size_t)m * N_NODES * 64;

    __shared__ __align__(16) unsigned short Abuf[64 * 64];     // 8 KB
    __shared__ __align__(16) unsigned short Bbuf[64 * 64];     // 8 KB
    __shared__ __align__(16) unsigned short tile16[64 * 72];   // 9.2 KB
    __shared__ unsigned colminLDS[4 * 64];                     // 1 KB

    const int t = threadIdx.x;
    const int wave = t >> 6, lane = t & 63;
    const int l15 = lane & 15, kg = lane >> 4;

    f32x4 acc[4] = {};
    #pragma unroll
    for (int half = 0; half < 2; half++) {
        const int koff = half * 64;
        if (half) __syncthreads();             // all chunk-0 frag reads done
        #pragma unroll
        for (int p = 0; p < 2; p++) {
            int f = t + p * 256;               // 0..511
            int r = f >> 3, c8 = f & 7;
            int slot = c8 ^ (r & 7);
            uint4 va = *(const uint4*)&X16[(size_t)(bi + r) * DIMS + koff + c8 * 8];
            *(uint4*)&Abuf[r * 64 + slot * 8] = va;
            uint4 vb = *(const uint4*)&X16[(size_t)(bj + r) * DIMS + koff + c8 * 8];
            *(uint4*)&Bbuf[r * 64 + slot * 8] = vb;
        }
        __syncthreads();

        const int rowA = wave * 16 + l15;
        short8 af0, af1;
        {
            int c8 = 0 * 4 + kg;
            af0 = *(const short8*)&Abuf[rowA * 64 + (c8 ^ (rowA & 7)) * 8];
            c8 = 1 * 4 + kg;
            af1 = *(const short8*)&Abuf[rowA * 64 + (c8 ^ (rowA & 7)) * 8];
        }
        #pragma unroll
        for (int n = 0; n < 4; n++) {
            const int rowB = n * 16 + l15;
            int c8 = 0 * 4 + kg;
            short8 bf0 = *(const short8*)&Bbuf[rowB * 64 + (c8 ^ (rowB & 7)) * 8];
            acc[n] = __builtin_amdgcn_mfma_f32_16x16x32_bf16(af0, bf0, acc[n], 0, 0, 0);
            c8 = 1 * 4 + kg;
            short8 bf1 = *(const short8*)&Bbuf[rowB * 64 + (c8 ^ (rowB & 7)) * 8];
            acc[n] = __builtin_amdgcn_mfma_f32_16x16x32_bf16(af1, bf1, acc[n], 0, 0, 0);
        }
    }

    const int r0 = wave * 16 + kg * 4;
    float sqi[4];
    #pragma unroll
    for (int rr = 0; rr < 4; rr++) sqi[rr] = sq[bi + r0 + rr];

    unsigned rowmin[4] = {U32_INF, U32_INF, U32_INF, U32_INF};   // (d16<<12)|globalcol
    unsigned colmin[4] = {U32_INF, U32_INF, U32_INF, U32_INF};   // (d16<<12)|localrow
    #pragma unroll
    for (int n = 0; n < 4; n++) {
        const int col = bj + n * 16 + l15;
        const float sqj = sq[col];
        #pragma unroll
        for (int rr = 0; rr < 4; rr++) {
            float d2 = sqi[rr] + sqj - 2.0f * acc[n][rr];
            unsigned hb = (unsigned)__half_as_ushort(__float2half(fmaxf(d2, EPSF)));
            const int cc = n * 16 + l15;
            const int R = r0 + rr;
            tile16[R * 72 + ((((cc >> 3) ^ (R & 7)) << 3) | (cc & 7))] = (unsigned short)hb;
            if ((bi + R) != col) {
                rowmin[rr] = u32min(rowmin[rr], (hb << 12) | (unsigned)col);
                colmin[n]  = u32min(colmin[n],  (hb << 12) | (unsigned)R);
            }
        }
    }
    #pragma unroll
    for (int rr = 0; rr < 4; rr++) {
        unsigned k = rowmin[rr];
        #pragma unroll
        for (int s = 8; s; s >>= 1) k = u32min(k, (unsigned)__shfl_xor((int)k, s));
        if (l15 == 0) {
            const unsigned row = (unsigned)(bi + r0 + rr);
            rt[(size_t)row * 64 + (bj >> 6)] = k;            // tile lower bound
            unsigned j = k & 0xFFFu, d16 = k >> 12;
            unsigned a = row < j ? row : j, b2 = row < j ? j : row;
            atomicMin(&br[row],
                ((unsigned long long)d16 << 24) | ((unsigned long long)a << 12) | b2);
        }
    }
    #pragma unroll
    for (int n = 0; n < 4; n++) {
        unsigned k = colmin[n];
        k = u32min(k, (unsigned)__shfl_xor((int)k, 16));
        k = u32min(k, (unsigned)__shfl_xor((int)k, 32));
        if (kg == 0) colminLDS[wave * 64 + n * 16 + l15] = k;
    }
    __syncthreads();

    #pragma unroll
    for (int q = 0; q < 2; q++) {
        int lin = t * 2 + q;
        int r = lin >> 3, k8 = lin & 7;
        uint4 v = *(const uint4*)&tile16[r * 72 + ((k8 ^ (r & 7)) << 3)];
        *(uint4*)&D[(size_t)(bi + r) * N_NODES + bj + k8 * 8] = v;
    }
    if (bi != bj) {
        #pragma unroll
        for (int q = 0; q < 2; q++) {
            int lin = t * 2 + q;
            int c = lin >> 3, r8 = lin & 7;
            unsigned w[4];
            #pragma unroll
            for (int h = 0; h < 4; h++) {
                int R0 = r8 * 8 + h * 2;
                int R1 = R0 + 1;
                unsigned lo = tile16[R0 * 72 + ((((c >> 3) ^ (R0 & 7)) << 3) | (c & 7))];
                unsigned hi = tile16[R1 * 72 + ((((c >> 3) ^ (R1 & 7)) << 3) | (c & 7))];
                w[h] = lo | (hi << 16);
            }
            uint4 v = make_uint4(w[0], w[1], w[2], w[3]);
            *(uint4*)&D[(size_t)(bj + c) * N_NODES + bi + r8 * 8] = v;
        }
        if (t < 64) {
            unsigned k = colminLDS[t];
            k = u32min(k, colminLDS[64 + t]);
            k = u32min(k, colminLDS[128 + t]);
            k = u32min(k, colminLDS[192 + t]);
            unsigned d16 = k >> 12, lrow = k & 0xFFFu;
            rt[(size_t)(bj + t) * 64 + (bi >> 6)] = (d16 << 12) | (unsigned)(bi + lrow);
            unsigned long long key64 = ((unsigned long long)d16 << 24) |
                ((unsigned long long)(bi + lrow) << 12) | (unsigned)(bj + t);
            atomicMin(&br[bj + t], key64);
        }
    }
}

// ---------------- Boruvka merge + prefill + worklist ----------------
// grid = 2 blocks (one per matrix), 1024 threads.
__global__ __launch_bounds__(1024) void boruvka_merge2(
        const unsigned short* __restrict__ comp_in,
        unsigned short* __restrict__ comp_out,
        const unsigned long long* __restrict__ bc_in,
        unsigned long long* __restrict__ bc_out,
        const unsigned long long* __restrict__ best_row,
        unsigned short* __restrict__ wlist,
        unsigned* __restrict__ wcount,
        float* __restrict__ deaths,
        unsigned* __restrict__ cnt,
        unsigned* __restrict__ done) {
    const int m = blockIdx.x;
    if (done[m]) return;
    const unsigned short* cin = comp_in + m * N_NODES;
    const unsigned long long* bi = bc_in + m * N_NODES;
    const unsigned long long* br = best_row + m * N_NODES;
    float* dth = deaths + m * N_NODES;

    __shared__ unsigned short s_mc[N_NODES];              // 8 KB comp (old->new)
    __shared__ unsigned short s_mp[N_NODES];              // 8 KB parent
    __shared__ unsigned long long s_bc[N_NODES];          // 32 KB
    __shared__ unsigned s_wc;

    const int t = threadIdx.x;
    for (int i = t; i < N_NODES; i += 1024) {
        s_mc[i] = cin[i];
        s_mp[i] = (unsigned short)i;
        s_bc[i] = bi[i];
    }
    if (t == 0) s_wc = 0;
    __syncthreads();

    for (int i = t; i < N_NODES; i += 1024) {
        unsigned long long k = s_bc[i];
        if (k != KEY_INF) {
            unsigned canon = (unsigned)(k & 0xFFFFFFu);
            unsigned a = canon >> 12, b = canon & 0xFFFu;
            unsigned ca = s_mc[a], cb = s_mc[b];
            unsigned other = (ca == (unsigned)i) ? cb : ca;
            s_mp[i] = (unsigned short)other;
            bool mutual = (s_bc[other] == k);
            if (!mutual || (unsigned)i < other) {
                unsigned idx = atomicAdd(&cnt[m], 1u);
                dth[idx] = half_bits_to_death((unsigned short)(k >> 24));
            }
        }
    }
    __syncthreads();

    unsigned nv[4];
    #pragma unroll
    for (int q = 0; q < 4; q++) {
        unsigned i = (unsigned)(t + q * 1024);
        unsigned p = s_mp[i], pp = s_mp[p];
        nv[q] = (pp == i) ? (i < p ? i : p) : p;
    }
    __syncthreads();
    #pragma unroll
    for (int q = 0; q < 4; q++) s_mp[t + q * 1024] = (unsigned short)nv[q];
    __syncthreads();

    #pragma unroll
    for (int q = 0; q < 4; q++) {
        unsigned rt = (unsigned)(t + q * 1024);
        unsigned p = s_mp[rt];
        while (p != rt) { rt = p; p = s_mp[rt]; }
        nv[q] = rt;
    }
    __syncthreads();
    #pragma unroll
    for (int q = 0; q < 4; q++) s_mp[t + q * 1024] = (unsigned short)nv[q];
    __syncthreads();

    #pragma unroll
    for (int q = 0; q < 4; q++) {
        int i = t + q * 1024;
        s_mc[i] = s_mp[s_mc[i]];
        s_bc[i] = KEY_INF;
    }
    __syncthreads();

    for (int i = t; i < N_NODES; i += 1024) {
        unsigned long long k = br[i];
        if (k != KEY_INF) {
            unsigned canon = (unsigned)(k & 0xFFFFFFu);
            unsigned a = canon >> 12, b = canon & 0xFFFu;
            unsigned j = (a == (unsigned)i) ? b : a;
            unsigned ci = s_mc[i];
            if (s_mc[j] != ci) {
                atomicMin(&s_bc[ci], k);
            } else {
                unsigned idx = atomicAdd(&s_wc, 1u);
                wlist[m * N_NODES + idx] = (unsigned short)i;
            }
        }
    }
    __syncthreads();

    for (int i = t; i < N_NODES; i += 1024) {
        comp_out[m * N_NODES + i] = s_mc[i];
        bc_out[m * N_NODES + i] = s_bc[i];
    }
    if (t == 0) {
        wcount[m] = s_wc;
        unsigned c = atomicAdd(&cnt[m], 0u);
        if (c >= N_NODES - 1) done[m] = 1u;
    }
}

// ---------------- worklist-driven scan ----------------
__global__ __launch_bounds__(1024) void boruvka_scanw(
        const unsigned short* __restrict__ D0,
        const unsigned short* __restrict__ D1,
        const unsigned short* __restrict__ comp16,
        const unsigned short* __restrict__ wlist,
        const unsigned* __restrict__ wcount,
        unsigned* __restrict__ rowtile,
        unsigned long long* __restrict__ best_row,
        unsigned long long* __restrict__ bc_scan,
        const unsigned* __restrict__ done) {
    const int m = blockIdx.y;
    if (done[m]) return;
    const unsigned count = wcount[m];
    if (blockIdx.x * 16 >= count) return;

    const unsigned short* __restrict__ D = m ? D1 : D0;
    const unsigned short* cm = comp16 + m * N_NODES;
    unsigned* rt = rowtile + (size_t)m * N_NODES * 64;
    unsigned long long* br = best_row + m * N_NODES;
    unsigned long long* bc = bc_scan + m * N_NODES;

    __shared__ __align__(16) unsigned short s_c16[N_NODES];   // 8 KB

    const int t = threadIdx.x;
    {
        uint2 v = ((const uint2*)cm)[t];
        *(uint2*)&s_c16[t * 4] = v;
    }
    __syncthreads();

    const int wave = t >> 6, lane = t & 63;
    const unsigned idx = blockIdx.x * 16 + wave;
    if (idx >= count) return;                   // wave-uniform
    const int r = (int)wlist[m * N_NODES + idx];
    const unsigned short ci16 = s_c16[r];

    const unsigned short* row = D + (size_t)r * N_NODES;
    unsigned* rtr = rt + (size_t)r * 64;
    unsigned tm = rtr[lane];
    unsigned long long bcv = bc[ci16];

    unsigned tmin = wave_min_u32(tm);
    if (bcv != KEY_INF && (tmin >> 12) > (unsigned)(bcv >> 24)) return;

    unsigned avail = tm;
    unsigned sel;
    sel = ((avail >> 12) << 6) | (unsigned)lane;
    sel = wave_min_u32(sel);
    const int t0 = (int)(sel & 63);
    if (lane == t0) avail = U32_INF;
    sel = ((avail >> 12) << 6) | (unsigned)lane;
    sel = wave_min_u32(sel);
    const int t1 = (int)(sel & 63);
    if (lane == t1) avail = U32_INF;
    sel = ((avail >> 12) << 6) | (unsigned)lane;
    sel = wave_min_u32(sel);
    const int t2 = (int)(sel & 63);
    if (lane == t2) avail = U32_INF;
    sel = ((avail >> 12) << 6) | (unsigned)lane;
    sel = wave_min_u32(sel);
    const int t3 = (int)(sel & 63);

    unsigned short dv0 = row[t0 * 64 + lane];
    unsigned short dv1 = row[t1 * 64 + lane];
    unsigned short dv2 = row[t2 * 64 + lane];
    unsigned short dv3 = row[t3 * 64 + lane];
    unsigned short cv0 = s_c16[t0 * 64 + lane];
    unsigned short cv1 = s_c16[t1 * 64 + lane];
    unsigned short cv2 = s_c16[t2 * 64 + lane];
    unsigned short cv3 = s_c16[t3 * 64 + lane];
    unsigned F0 = wave_min_u32((cv0 != ci16) ? (((unsigned)dv0 << 12) | (unsigned)(t0 * 64 + lane)) : U32_INF);
    unsigned F1 = wave_min_u32((cv1 != ci16) ? (((unsigned)dv1 << 12) | (unsigned)(t1 * 64 + lane)) : U32_INF);
    unsigned F2 = wave_min_u32((cv2 != ci16) ? (((unsigned)dv2 << 12) | (unsigned)(t2 * 64 + lane)) : U32_INF);
    unsigned F3 = wave_min_u32((cv3 != ci16) ? (((unsigned)dv3 << 12) | (unsigned)(t3 * 64 + lane)) : U32_INF);
    unsigned B = u32min(u32min(F0, F1), u32min(F2, F3));
    if (lane == 0) { rtr[t0] = F0; rtr[t1] = F1; rtr[t2] = F2; rtr[t3] = F3; }
    if (lane == t0) tm = F0;
    if (lane == t1) tm = F1;
    if (lane == t2) tm = F2;
    if (lane == t3) tm = F3;

    unsigned long long need = __ballot(tm < B);
    if (need) {
        if (__popcll(need) > 6) {
            unsigned best32 = B;
            const unsigned cirep = (unsigned)ci16 | ((unsigned)ci16 << 16);
            #pragma unroll 4
            for (int it = 0; it < 8; it++) {
                const int e0 = it * 512 + lane * 8;
                uint4 dvv = *(const uint4*)&row[e0];
                uint4 cvv = *(const uint4*)&s_c16[e0];
                unsigned px = cvv.x ^ cirep, py = cvv.y ^ cirep;
                unsigned pz = cvv.z ^ cirep, pw = cvv.w ^ cirep;
                if (px | py | pz | pw) {
                    unsigned dws[4] = {dvv.x, dvv.y, dvv.z, dvv.w};
                    unsigned pp[4] = {px, py, pz, pw};
                    #pragma unroll
                    for (int h = 0; h < 4; h++) {
                        unsigned j0 = (unsigned)(e0 + h * 2);
                        if (pp[h] & 0xFFFFu)
                            best32 = u32min(best32, ((dws[h] & 0xFFFFu) << 12) | j0);
                        if (pp[h] >> 16)
                            best32 = u32min(best32, ((dws[h] >> 16) << 12) | (j0 + 1));
                    }
                }
            }
            B = wave_min_u32(best32);
        } else {
            while (need) {
                const int tl = __ffsll((unsigned long long)need) - 1;
                need &= need - 1;
                unsigned bnd = (unsigned)__shfl((int)tm, tl);
                if (bnd >= B) continue;
                unsigned short dv = row[tl * 64 + lane];
                unsigned short cv = s_c16[tl * 64 + lane];
                unsigned f = wave_min_u32((cv != ci16)
                    ? (((unsigned)dv << 12) | (unsigned)(tl * 64 + lane)) : U32_INF);
                if (lane == 0) rtr[tl] = f;
                B = u32min(B, f);
            }
        }
    }

    unsigned long long cached;
    if (B != U32_INF) {
        unsigned j = B & 0xFFFu, d16 = B >> 12;
        unsigned a = (unsigned)r < j ? (unsigned)r : j;
        unsigned b2 = (unsigned)r < j ? j : (unsigned)r;
        cached = ((unsigned long long)d16 << 24) | ((unsigned long long)a << 12) | b2;
    } else {
        cached = KEY_INF;
    }
    if (lane == 0) {
        br[r] = cached;
        if (cached != KEY_INF) atomicMin(&bc[ci16], cached);
    }
}

// ---------------- persistent tail: finishes all remaining rounds -------------
__device__ inline void tail_process_mask(unsigned long long mask, int rowbase,
                                         const unsigned short* __restrict__ D,
                                         unsigned* __restrict__ rt,
                                         unsigned short* s_c,
                                         unsigned long long* s_br,
                                         unsigned long long* s_bc,
                                         int lane) {
    while (mask) {
        const int l = __ffsll(mask) - 1; mask &= mask - 1;
        const int r = rowbase + l;
        const unsigned short ci16 = s_c[r];
        unsigned* rtr = rt + (size_t)r * 64;
        unsigned tm = rtr[lane];
        unsigned tmin = wave_min_u32(tm);
        unsigned long long bcv = s_bc[ci16];
        if (bcv != KEY_INF && (tmin >> 12) > (unsigned)(bcv >> 24)) continue;
        const unsigned short* row = D + (size_t)r * N_NODES;
        bool scanned = false;
        unsigned B = U32_INF;
        for (int it = 0; it < 64; ++it) {
            unsigned long long my =
                ((unsigned long long)(scanned ? U32_INF : tm) << 8) | (unsigned)lane;
            #pragma unroll
            for (int s = 32; s; s >>= 1) my = u64min(my, shfl_xor_u64(my, s));
            unsigned wtm = (unsigned)(my >> 8);
            if (wtm >= B) break;
            const int tl = (int)(my & 0xFFu);
            unsigned short dv = row[tl * 64 + lane];
            unsigned short cv = s_c[tl * 64 + lane];
            unsigned f = wave_min_u32((cv != ci16)
                ? (((unsigned)dv << 12) | (unsigned)(tl * 64 + lane)) : U32_INF);
            if (lane == tl) { scanned = true; tm = f; }
            if (lane == 0) rtr[tl] = f;
            B = u32min(B, f);
        }
        if (lane == 0) {
            if (B != U32_INF) {
                unsigned j = B & 0xFFFu, d16 = B >> 12;
                unsigned a = (unsigned)r < j ? (unsigned)r : j;
                unsigned b2 = (unsigned)r < j ? j : (unsigned)r;
                unsigned long long key = ((unsigned long long)d16 << 24) |
                    ((unsigned long long)a << 12) | b2;
                s_br[r] = key;
                atomicMin(&s_bc[ci16], key);
            } else {
                s_br[r] = KEY_INF;
            }
        }
    }
}

__global__ __launch_bounds__(1024) void boruvka_tail(const unsigned short* __restrict__ D0,
                                                     const unsigned short* __restrict__ D1,
                                                     unsigned short* __restrict__ comp16,
                                                     unsigned* __restrict__ rowtile,
                                                     unsigned long long* __restrict__ best_row,
                                                     float* __restrict__ deaths,
                                                     unsigned* __restrict__ cnt,
                                                     unsigned* __restrict__ done) {
    const int m = blockIdx.x;
    if (done[m]) return;
    const unsigned short* __restrict__ D = m ? D1 : D0;
    unsigned* rt = rowtile + (size_t)m * N_NODES * 64;
    float* dth = deaths + m * N_NODES;

    __shared__ unsigned short s_c[N_NODES];
    __shared__ unsigned short s_mp[N_NODES];
    __shared__ unsigned long long s_br[N_NODES];
    __shared__ unsigned long long s_bc[N_NODES];
    __shared__ unsigned s_cnt;

    const int t = threadIdx.x;
    const int wave = t >> 6, lane = t & 63;

    for (int i = t; i < N_NODES; i += 1024) {
        s_c[i] = comp16[m * N_NODES + i];
        s_br[i] = best_row[m * N_NODES + i];
        s_bc[i] = KEY_INF;
    }
    if (t == 0) s_cnt = cnt[m];
    __syncthreads();

    for (int round = 0; round < 16; ++round) {
        unsigned long long pend[4];
        #pragma unroll
        for (int b = 0; b < 4; b++) {
            const int rr = wave * 256 + b * 64 + lane;
            unsigned long long k = s_br[rr];
            bool need = false;
            if (k != KEY_INF) {
                unsigned canon = (unsigned)(k & 0xFFFFFFu);
                unsigned a = canon >> 12, bb = canon & 0xFFFu;
                unsigned j = (a == (unsigned)rr) ? bb : a;
                if (s_c[j] == s_c[rr]) need = true;
                else atomicMin(&s_bc[s_c[rr]], k);
            }
            pend[b] = __ballot(need);
            s_mp[rr] = (unsigned short)rr;
        }
        __syncthreads();

        #pragma unroll
        for (int b = 0; b < 4; b++)
            tail_process_mask(pend[b], wave * 256 + b * 64, D, rt, s_c, s_br, s_bc, lane);
        __syncthreads();

        for (int i = t; i < N_NODES; i += 1024) {
            unsigned long long k = s_bc[i];
            if (k != KEY_INF) {
                unsigned canon = (unsigned)(k & 0xFFFFFFu);
                unsigned a = canon >> 12, b = canon & 0xFFFu;
                unsigned ca = s_c[a], cb = s_c[b];
                unsigned other = (ca == (unsigned)i) ? cb : ca;
                s_mp[i] = (unsigned short)other;
                bool mutual = (s_bc[other] == k);
                if (!mutual || (unsigned)i < other) {
                    unsigned idx = atomicAdd(&s_cnt, 1u);
                    dth[idx] = half_bits_to_death((unsigned short)(k >> 24));
                }
            }
        }
        __syncthreads();

        unsigned nv[4];
        #pragma unroll
        for (int q = 0; q < 4; q++) {
            unsigned i = (unsigned)(t + q * 1024);
            unsigned p = s_mp[i], pp = s_mp[p];
            nv[q] = (pp == i) ? (i < p ? i : p) : p;
        }
        __syncthreads();
        #pragma unroll
        for (int q = 0; q < 4; q++) s_mp[t + q * 1024] = (unsigned short)nv[q];
        __syncthreads();
        #pragma unroll
        for (int q = 0; q < 4; q++) {
            unsigned rr = (unsigned)(t + q * 1024);
            unsigned p = s_mp[rr];
            while (p != rr) { rr = p; p = s_mp[rr]; }
            nv[q] = rr;
        }
        __syncthreads();
        #pragma unroll
        for (int q = 0; q < 4; q++) s_mp[t + q * 1024] = (unsigned short)nv[q];
        __syncthreads();

        for (int i = t; i < N_NODES; i += 1024) {
            s_c[i] = s_mp[s_c[i]];
            s_bc[i] = KEY_INF;
        }
        __syncthreads();
        if (s_cnt >= N_NODES - 1) break;
    }

    for (int i = t; i < N_NODES; i += 1024) {
        comp16[m * N_NODES + i] = s_c[i];
        best_row[m * N_NODES + i] = s_br[i];
    }
    if (t == 0) {
        cnt[m] = s_cnt;
        if (s_cnt >= N_NODES - 1) done[m] = 1u;
    }
}

// ---------------- sort (hybrid bitonic) + last-block finalize ----------------
__global__ __launch_bounds__(1024) void sortfinal_kernel(float* __restrict__ deaths,
                                                         const float* __restrict__ partials,
                                                         unsigned* __restrict__ sctl,
                                                         float* __restrict__ out) {
    float* d = deaths + blockIdx.x * N_NODES;
    __shared__ float s[N_NODES];
    __shared__ float red[16], red2[16];
    __shared__ int s_last;
    const int t = threadIdx.x;
    if (t == 0) s_last = 0;
    for (int i = t; i < N_NODES - 1; i += 1024) s[i] = d[i];
    if (t == 0) s[N_NODES - 1] = BIGF;
    __syncthreads();

    {
        float v[4];
        #pragma unroll
        for (int q = 0; q < 4; q++) v[q] = s[t + q * 1024];
        #pragma unroll
        for (int k = 2; k <= 32; k <<= 1) {
            for (int j = k >> 1; j; j >>= 1) {
                #pragma unroll
                for (int q = 0; q < 4; q++) {
                    float o = __shfl_xor(v[q], j);
                    bool up  = (t & j) == 0;
                    bool asc = (((t + q * 1024) & k) == 0);
                    float lo = fminf(v[q], o), hi = fmaxf(v[q], o);
                    v[q] = (asc == up) ? lo : hi;
                }
            }
        }
        #pragma unroll
        for (int q = 0; q < 4; q++) s[t + q * 1024] = v[q];
    }
    __syncthreads();

    for (int k = 64; k <= N_NODES; k <<= 1) {
        for (int j = k >> 1; j >= 64; j >>= 1) {
            #pragma unroll
            for (int q = 0; q < 4; q++) {
                int i = t + q * 1024;
                int p = i ^ j;
                if (p > i) {
                    float a = s[i], b = s[p];
                    bool asc = (i & k) == 0;
                    if ((a > b) == asc) { s[i] = b; s[p] = a; }
                }
            }
            __syncthreads();
        }
        float v[4];
        #pragma unroll
        for (int q = 0; q < 4; q++) v[q] = s[t + q * 1024];
        for (int j = 32; j; j >>= 1) {
            #pragma unroll
            for (int q = 0; q < 4; q++) {
                float o = __shfl_xor(v[q], j);
                bool up  = (t & j) == 0;
                bool asc = (((t + q * 1024) & k) == 0);
                float lo = fminf(v[q], o), hi = fmaxf(v[q], o);
                v[q] = (asc == up) ? lo : hi;
            }
        }
        #pragma unroll
        for (int q = 0; q < 4; q++) s[t + q * 1024] = v[q];
        __syncthreads();
    }
    for (int i = t; i < N_NODES - 1; i += 1024) d[i] = s[i];

    __threadfence();
    __syncthreads();
    if (t == 0) {
        unsigned old = atomicAdd(sctl, 1u);
        if (old == 1) s_last = 1;
    }
    __syncthreads();
    if (!s_last) return;
    __threadfence();

    float a = 0.f;
    for (int i = t; i < N_NODES - 1; i += 1024) {
        float x = __uint_as_float(atomicAdd((unsigned*)&deaths[i], 0u));
        float y = __uint_as_float(atomicAdd((unsigned*)&deaths[N_NODES + i], 0u));
        float dd = x - y;
        a += dd * dd;
    }
    float rsum = (t < 512) ? partials[t] : 0.f;
    #pragma unroll
    for (int off = 32; off; off >>= 1) { a += __shfl_xor(a, off); rsum += __shfl_xor(rsum, off); }
    if ((t & 63) == 0) { red[t >> 6] = a; red2[t >> 6] = rsum; }
    __syncthreads();
    if (t == 0) {
        float topo_sum = 0.f, repr_sum = 0.f;
        #pragma unroll
        for (int i = 0; i < 16; i++) { topo_sum += red[i]; repr_sum += red2[i]; }
        float repr = repr_sum / (float)(N_NODES * DIMS);
        float topo = topo_sum / (float)(2 * (N_NODES - 1));
        out[0] = 0.5f * repr + 0.5f * topo;
        out[1] = repr;
        out[2] = topo;
    }
}

// ---------------- host ----------------

extern "C" void kernel_launch(void* const* d_in, const int* in_sizes, int n_in,
                              void* d_out, int out_size, void* d_ws, size_t ws_size,
                              hipStream_t stream) {
    const float* S = (const float*)d_in[0];
    const float* T = (const float*)d_in[1];
    float* out = (float*)d_out;

    const size_t nn = (size_t)N_NODES * N_NODES;
    char* p = (char*)d_ws;
    __half* Ds = (__half*)p;                   p += nn * 2;
    __half* Dt = (__half*)p;                   p += nn * 2;
    unsigned short* X16s = (unsigned short*)p; p += (size_t)N_NODES * DIMS * 2;
    unsigned short* X16t = (unsigned short*)p; p += (size_t)N_NODES * DIMS * 2;
    unsigned long long* bcA = (unsigned long long*)p; p += (size_t)2 * N_NODES * 8;
    unsigned long long* bcB = (unsigned long long*)p; p += (size_t)2 * N_NODES * 8;
    unsigned long long* best_row = (unsigned long long*)p; p += 2 * N_NODES * 8;
    unsigned* rowtile  = (unsigned*)p; p += (size_t)2 * N_NODES * 64 * 4;
    float*    sqs      = (float*)p;    p += N_NODES * 4;
    float*    sqt      = (float*)p;    p += N_NODES * 4;
    float*    deaths   = (float*)p;    p += 2 * N_NODES * 4;
    float*    partials = (float*)p;    p += 512 * 4;
    unsigned short* cb0 = (unsigned short*)p; p += 2 * N_NODES * 2;
    unsigned short* cb1 = (unsigned short*)p; p += 2 * N_NODES * 2;
    unsigned short* wlist = (unsigned short*)p; p += 2 * N_NODES * 2;
    unsigned* wcount   = (unsigned*)p; p += 2 * 4;
    unsigned* cnt      = (unsigned*)p; p += 2 * 4;
    unsigned* done     = (unsigned*)p; p += 2 * 4;
    unsigned* sctl     = (unsigned*)p;

    unsigned long long* bcbuf[2] = { bcA, bcB };
    unsigned short* cbuf[2] = { cb0, cb1 };

    prep_kernel<<<N_NODES / 8, 256, 0, stream>>>(S, T, X16s, X16t, sqs, sqt, partials,
                                                 cb0, best_row, cnt, done, sctl);

    dim3 dg(N_NODES / 64, N_NODES / 64, 2);
    dist_kernel<<<dg, 256, 0, stream>>>(X16s, X16t, sqs, sqt, Ds, Dt, best_row, rowtile);

    // merge0: comps identity -> bc == best_row directly
    boruvka_merge2<<<2, 1024, 0, stream>>>(cb0, cb1, best_row, bcbuf[1], best_row,
                                           wlist, wcount, deaths, cnt, done);

    // 2 wide rounds (the heavy ones), then the persistent tail finishes.
    dim3 sg(N_NODES / 16, 2);
    for (int k = 1; k <= 2; k++) {
        boruvka_scanw<<<sg, 1024, 0, stream>>>((const unsigned short*)Ds,
                                               (const unsigned short*)Dt,
                                               cbuf[k & 1], wlist, wcount, rowtile,
                                               best_row, bcbuf[k & 1], done);
        boruvka_merge2<<<2, 1024, 0, stream>>>(cbuf[k & 1], cbuf[(k + 1) & 1],
                                               bcbuf[k & 1], bcbuf[(k + 1) & 1], best_row,
                                               wlist, wcount, deaths, cnt, done);
    }
    // after merge2, comps live in cb1; tail runs all remaining rounds in-LDS
    boruvka_tail<<<2, 1024, 0, stream>>>((const unsigned short*)Ds,
                                         (const unsigned short*)Dt,
                                         cb1, rowtile, best_row, deaths, cnt, done);
    sortfinal_kernel<<<2, 1024, 0, stream>>>(deaths, partials, sctl, out);
}

// Round 21
// 156.703 us; speedup vs baseline: 1.3416x; 1.3416x over previous
//
#include <hip/hip_runtime.h>
#include <hip/hip_fp16.h>

#define N_NODES 4096
#define DIMS 128

typedef __attribute__((ext_vector_type(8))) short short8;
typedef __attribute__((ext_vector_type(4))) float f32x4;

static constexpr float BIGF = 1e9f;
static constexpr float EPSF = 1e-12f;
static constexpr unsigned long long KEY_INF = ~0ull;
static constexpr unsigned U32_INF = 0xFFFFFFFFu;

// ---------------- helpers ----------------

__device__ inline unsigned short f32_to_bf16(float f) {
    unsigned u = __float_as_uint(f);
    unsigned r = (u + 0x7FFFu + ((u >> 16) & 1u)) >> 16;   // RNE
    return (unsigned short)r;
}

// D stores fp16(d^2); deaths decode with sqrt at emit time.
__device__ inline float half_bits_to_death(unsigned short b) {
    __half h;
    __builtin_memcpy(&h, &b, 2);
    return sqrtf(__half2float(h));
}

__device__ inline unsigned u32min(unsigned a, unsigned b) { return a < b ? a : b; }

__device__ inline unsigned long long u64min(unsigned long long a, unsigned long long b) {
    return a < b ? a : b;
}

__device__ inline unsigned long long shfl_xor_u64(unsigned long long v, int m) {
    int lo = __shfl_xor((int)(unsigned)(v & 0xFFFFFFFFull), m);
    int hi = __shfl_xor((int)(unsigned)(v >> 32), m);
    return ((unsigned long long)(unsigned)hi << 32) | (unsigned)lo;
}

__device__ inline unsigned wave_min_u32(unsigned v) {
    #pragma unroll
    for (int s = 32; s; s >>= 1) v = u32min(v, (unsigned)__shfl_xor((int)v, s));
    return v;
}

__device__ inline float block_reduce_sum_256(float v) {
    __shared__ float s[4];
    __syncthreads();
    #pragma unroll
    for (int off = 32; off; off >>= 1) v += __shfl_xor(v, off);
    if ((threadIdx.x & 63) == 0) s[threadIdx.x >> 6] = v;
    __syncthreads();
    return s[0] + s[1] + s[2] + s[3];
}

// ---------------- prep: bf16 convert, norms, repr partials, init ----------------
// grid 512 x 256
__global__ __launch_bounds__(256) void prep_kernel(const float* __restrict__ S,
                                                   const float* __restrict__ T,
                                                   unsigned short* __restrict__ X16s,
                                                   unsigned short* __restrict__ X16t,
                                                   float* __restrict__ sqs,
                                                   float* __restrict__ sqt,
                                                   float* __restrict__ partials,
                                                   unsigned short* __restrict__ comp0,
                                                   unsigned long long* __restrict__ best_row,
                                                   unsigned* __restrict__ cnt,
                                                   unsigned* __restrict__ done,
                                                   unsigned* __restrict__ sctl) {
    const int t = threadIdx.x;
    const int gid = blockIdx.x * 256 + t;
    if (gid < 2 * N_NODES) {
        comp0[gid] = (unsigned short)(gid & (N_NODES - 1));
        best_row[gid] = KEY_INF;               // dist epilogue atomicMins real edges in
    }
    if (gid < 2) { cnt[gid] = 0; done[gid] = 0; }
    if (gid == 0) sctl[0] = 0;

    const int wave = t >> 6, lane = t & 63;
    const int row = blockIdx.x * 8 + wave * 2 + (lane >> 5);
    const int c4 = (lane & 31) * 4;
    const size_t off = (size_t)row * DIMS + c4;
    float4 a = *(const float4*)&S[off];
    float4 b = *(const float4*)&T[off];
    float sa = a.x * a.x + a.y * a.y + a.z * a.z + a.w * a.w;
    float sb = b.x * b.x + b.y * b.y + b.z * b.z + b.w * b.w;
    #pragma unroll
    for (int m = 16; m; m >>= 1) { sa += __shfl_xor(sa, m); sb += __shfl_xor(sb, m); }
    if ((lane & 31) == 0) { sqs[row] = sa; sqt[row] = sb; }
    ushort4 oa, ob;
    oa.x = f32_to_bf16(a.x); oa.y = f32_to_bf16(a.y);
    oa.z = f32_to_bf16(a.z); oa.w = f32_to_bf16(a.w);
    ob.x = f32_to_bf16(b.x); ob.y = f32_to_bf16(b.y);
    ob.z = f32_to_bf16(b.z); ob.w = f32_to_bf16(b.w);
    *(ushort4*)&X16s[off] = oa;
    *(ushort4*)&X16t[off] = ob;
    float dx = a.x - b.x, dy = a.y - b.y, dz = a.z - b.z, dw = a.w - b.w;
    float rs = block_reduce_sum_256(dx * dx + dy * dy + dz * dz + dw * dw);
    if (t == 0) partials[blockIdx.x] = rs;
}

// ---------------- distance matrix: triangular MFMA, rowtile mins --------------
// K staged in two 64-dim chunks (26.6 KB LDS -> 6 blocks/CU); D stores fp16(d^2).
__global__ __launch_bounds__(256) void dist_kernel(const unsigned short* __restrict__ X16s,
                                                   const unsigned short* __restrict__ X16t,
                                                   const float* __restrict__ sqs,
                                                   const float* __restrict__ sqt,
                                                   __half* __restrict__ Ds,
                                                   __half* __restrict__ Dt,
                                                   unsigned long long* __restrict__ best_row,
                                                   unsigned* __restrict__ rowtile) {
    const int bi = blockIdx.y * 64;
    const int bj = blockIdx.x * 64;
    if (bj < bi) return;
    const int m = blockIdx.z;
    const unsigned short* __restrict__ X16 = m ? X16t : X16s;
    const float* __restrict__ sq = m ? sqt : sqs;
    unsigned short* __restrict__ D = (unsigned short*)(m ? Dt : Ds);
    unsigned long long* br = best_row + m * N_NODES;
    unsigned* rt = rowtile + (size_t)m * N_NODES * 64;

    __shared__ __align__(16) unsigned short Abuf[64 * 64];     // 8 KB
    __shared__ __align__(16) unsigned short Bbuf[64 * 64];     // 8 KB
    __shared__ __align__(16) unsigned short tile16[64 * 72];   // 9.2 KB
    __shared__ unsigned colminLDS[4 * 64];                     // 1 KB

    const int t = threadIdx.x;
    const int wave = t >> 6, lane = t & 63;
    const int l15 = lane & 15, kg = lane >> 4;

    f32x4 acc[4] = {};
    #pragma unroll
    for (int half = 0; half < 2; half++) {
        const int koff = half * 64;
        if (half) __syncthreads();             // all chunk-0 frag reads done
        #pragma unroll
        for (int p = 0; p < 2; p++) {
            int f = t + p * 256;               // 0..511
            int r = f >> 3, c8 = f & 7;
            int slot = c8 ^ (r & 7);
            uint4 va = *(const uint4*)&X16[(size_t)(bi + r) * DIMS + koff + c8 * 8];
            *(uint4*)&Abuf[r * 64 + slot * 8] = va;
            uint4 vb = *(const uint4*)&X16[(size_t)(bj + r) * DIMS + koff + c8 * 8];
            *(uint4*)&Bbuf[r * 64 + slot * 8] = vb;
        }
        __syncthreads();

        const int rowA = wave * 16 + l15;
        short8 af0, af1;
        {
            int c8 = 0 * 4 + kg;
            af0 = *(const short8*)&Abuf[rowA * 64 + (c8 ^ (rowA & 7)) * 8];
            c8 = 1 * 4 + kg;
            af1 = *(const short8*)&Abuf[rowA * 64 + (c8 ^ (rowA & 7)) * 8];
        }
        #pragma unroll
        for (int n = 0; n < 4; n++) {
            const int rowB = n * 16 + l15;
            int c8 = 0 * 4 + kg;
            short8 bf0 = *(const short8*)&Bbuf[rowB * 64 + (c8 ^ (rowB & 7)) * 8];
            acc[n] = __builtin_amdgcn_mfma_f32_16x16x32_bf16(af0, bf0, acc[n], 0, 0, 0);
            c8 = 1 * 4 + kg;
            short8 bf1 = *(const short8*)&Bbuf[rowB * 64 + (c8 ^ (rowB & 7)) * 8];
            acc[n] = __builtin_amdgcn_mfma_f32_16x16x32_bf16(af1, bf1, acc[n], 0, 0, 0);
        }
    }

    const int r0 = wave * 16 + kg * 4;
    float sqi[4];
    #pragma unroll
    for (int rr = 0; rr < 4; rr++) sqi[rr] = sq[bi + r0 + rr];

    unsigned rowmin[4] = {U32_INF, U32_INF, U32_INF, U32_INF};   // (d16<<12)|globalcol
    unsigned colmin[4] = {U32_INF, U32_INF, U32_INF, U32_INF};   // (d16<<12)|localrow
    #pragma unroll
    for (int n = 0; n < 4; n++) {
        const int col = bj + n * 16 + l15;
        const float sqj = sq[col];
        #pragma unroll
        for (int rr = 0; rr < 4; rr++) {
            float d2 = sqi[rr] + sqj - 2.0f * acc[n][rr];
            unsigned hb = (unsigned)__half_as_ushort(__float2half(fmaxf(d2, EPSF)));
            const int cc = n * 16 + l15;
            const int R = r0 + rr;
            tile16[R * 72 + ((((cc >> 3) ^ (R & 7)) << 3) | (cc & 7))] = (unsigned short)hb;
            if ((bi + R) != col) {
                rowmin[rr] = u32min(rowmin[rr], (hb << 12) | (unsigned)col);
                colmin[n]  = u32min(colmin[n],  (hb << 12) | (unsigned)R);
            }
        }
    }
    #pragma unroll
    for (int rr = 0; rr < 4; rr++) {
        unsigned k = rowmin[rr];
        #pragma unroll
        for (int s = 8; s; s >>= 1) k = u32min(k, (unsigned)__shfl_xor((int)k, s));
        if (l15 == 0) {
            const unsigned row = (unsigned)(bi + r0 + rr);
            rt[(size_t)row * 64 + (bj >> 6)] = k;            // tile lower bound
            unsigned j = k & 0xFFFu, d16 = k >> 12;
            unsigned a = row < j ? row : j, b2 = row < j ? j : row;
            atomicMin(&br[row],
                ((unsigned long long)d16 << 24) | ((unsigned long long)a << 12) | b2);
        }
    }
    #pragma unroll
    for (int n = 0; n < 4; n++) {
        unsigned k = colmin[n];
        k = u32min(k, (unsigned)__shfl_xor((int)k, 16));
        k = u32min(k, (unsigned)__shfl_xor((int)k, 32));
        if (kg == 0) colminLDS[wave * 64 + n * 16 + l15] = k;
    }
    __syncthreads();

    #pragma unroll
    for (int q = 0; q < 2; q++) {
        int lin = t * 2 + q;
        int r = lin >> 3, k8 = lin & 7;
        uint4 v = *(const uint4*)&tile16[r * 72 + ((k8 ^ (r & 7)) << 3)];
        *(uint4*)&D[(size_t)(bi + r) * N_NODES + bj + k8 * 8] = v;
    }
    if (bi != bj) {
        #pragma unroll
        for (int q = 0; q < 2; q++) {
            int lin = t * 2 + q;
            int c = lin >> 3, r8 = lin & 7;
            unsigned w[4];
            #pragma unroll
            for (int h = 0; h < 4; h++) {
                int R0 = r8 * 8 + h * 2;
                int R1 = R0 + 1;
                unsigned lo = tile16[R0 * 72 + ((((c >> 3) ^ (R0 & 7)) << 3) | (c & 7))];
                unsigned hi = tile16[R1 * 72 + ((((c >> 3) ^ (R1 & 7)) << 3) | (c & 7))];
                w[h] = lo | (hi << 16);
            }
            uint4 v = make_uint4(w[0], w[1], w[2], w[3]);
            *(uint4*)&D[(size_t)(bj + c) * N_NODES + bi + r8 * 8] = v;
        }
        if (t < 64) {
            unsigned k = colminLDS[t];
            k = u32min(k, colminLDS[64 + t]);
            k = u32min(k, colminLDS[128 + t]);
            k = u32min(k, colminLDS[192 + t]);
            unsigned d16 = k >> 12, lrow = k & 0xFFFu;
            rt[(size_t)(bj + t) * 64 + (bi >> 6)] = (d16 << 12) | (unsigned)(bi + lrow);
            unsigned long long key64 = ((unsigned long long)d16 << 24) |
                ((unsigned long long)(bi + lrow) << 12) | (unsigned)(bj + t);
            atomicMin(&br[bj + t], key64);
        }
    }
}

// ---------------- Boruvka merge + prefill + worklist ----------------
// grid = 2 blocks (one per matrix), 1024 threads.
__global__ __launch_bounds__(1024) void boruvka_merge2(
        const unsigned short* __restrict__ comp_in,
        unsigned short* __restrict__ comp_out,
        const unsigned long long* __restrict__ bc_in,
        unsigned long long* __restrict__ bc_out,
        const unsigned long long* __restrict__ best_row,
        unsigned short* __restrict__ wlist,
        unsigned* __restrict__ wcount,
        float* __restrict__ deaths,
        unsigned* __restrict__ cnt,
        unsigned* __restrict__ done) {
    const int m = blockIdx.x;
    if (done[m]) return;
    const unsigned short* cin = comp_in + m * N_NODES;
    const unsigned long long* bi = bc_in + m * N_NODES;
    const unsigned long long* br = best_row + m * N_NODES;
    float* dth = deaths + m * N_NODES;

    __shared__ unsigned short s_mc[N_NODES];              // 8 KB comp (old->new)
    __shared__ unsigned short s_mp[N_NODES];              // 8 KB parent
    __shared__ unsigned long long s_bc[N_NODES];          // 32 KB
    __shared__ unsigned s_wc;

    const int t = threadIdx.x;
    for (int i = t; i < N_NODES; i += 1024) {
        s_mc[i] = cin[i];
        s_mp[i] = (unsigned short)i;
        s_bc[i] = bi[i];
    }
    if (t == 0) s_wc = 0;
    __syncthreads();

    for (int i = t; i < N_NODES; i += 1024) {
        unsigned long long k = s_bc[i];
        if (k != KEY_INF) {
            unsigned canon = (unsigned)(k & 0xFFFFFFu);
            unsigned a = canon >> 12, b = canon & 0xFFFu;
            unsigned ca = s_mc[a], cb = s_mc[b];
            unsigned other = (ca == (unsigned)i) ? cb : ca;
            s_mp[i] = (unsigned short)other;
            bool mutual = (s_bc[other] == k);
            if (!mutual || (unsigned)i < other) {
                unsigned idx = atomicAdd(&cnt[m], 1u);
                dth[idx] = half_bits_to_death((unsigned short)(k >> 24));
            }
        }
    }
    __syncthreads();

    unsigned nv[4];
    #pragma unroll
    for (int q = 0; q < 4; q++) {
        unsigned i = (unsigned)(t + q * 1024);
        unsigned p = s_mp[i], pp = s_mp[p];
        nv[q] = (pp == i) ? (i < p ? i : p) : p;
    }
    __syncthreads();
    #pragma unroll
    for (int q = 0; q < 4; q++) s_mp[t + q * 1024] = (unsigned short)nv[q];
    __syncthreads();

    #pragma unroll
    for (int q = 0; q < 4; q++) {
        unsigned rt = (unsigned)(t + q * 1024);
        unsigned p = s_mp[rt];
        while (p != rt) { rt = p; p = s_mp[rt]; }
        nv[q] = rt;
    }
    __syncthreads();
    #pragma unroll
    for (int q = 0; q < 4; q++) s_mp[t + q * 1024] = (unsigned short)nv[q];
    __syncthreads();

    #pragma unroll
    for (int q = 0; q < 4; q++) {
        int i = t + q * 1024;
        s_mc[i] = s_mp[s_mc[i]];
        s_bc[i] = KEY_INF;
    }
    __syncthreads();

    for (int i = t; i < N_NODES; i += 1024) {
        unsigned long long k = br[i];
        if (k != KEY_INF) {
            unsigned canon = (unsigned)(k & 0xFFFFFFu);
            unsigned a = canon >> 12, b = canon & 0xFFFu;
            unsigned j = (a == (unsigned)i) ? b : a;
            unsigned ci = s_mc[i];
            if (s_mc[j] != ci) {
                atomicMin(&s_bc[ci], k);
            } else {
                unsigned idx = atomicAdd(&s_wc, 1u);
                wlist[m * N_NODES + idx] = (unsigned short)i;
            }
        }
    }
    __syncthreads();

    for (int i = t; i < N_NODES; i += 1024) {
        comp_out[m * N_NODES + i] = s_mc[i];
        bc_out[m * N_NODES + i] = s_bc[i];
    }
    if (t == 0) {
        wcount[m] = s_wc;
        unsigned c = atomicAdd(&cnt[m], 0u);
        if (c >= N_NODES - 1) done[m] = 1u;
    }
}

// ---------------- worklist-driven scan ----------------
__global__ __launch_bounds__(1024) void boruvka_scanw(
        const unsigned short* __restrict__ D0,
        const unsigned short* __restrict__ D1,
        const unsigned short* __restrict__ comp16,
        const unsigned short* __restrict__ wlist,
        const unsigned* __restrict__ wcount,
        unsigned* __restrict__ rowtile,
        unsigned long long* __restrict__ best_row,
        unsigned long long* __restrict__ bc_scan,
        const unsigned* __restrict__ done) {
    const int m = blockIdx.y;
    if (done[m]) return;
    const unsigned count = wcount[m];
    if (blockIdx.x * 16 >= count) return;

    const unsigned short* __restrict__ D = m ? D1 : D0;
    const unsigned short* cm = comp16 + m * N_NODES;
    unsigned* rt = rowtile + (size_t)m * N_NODES * 64;
    unsigned long long* br = best_row + m * N_NODES;
    unsigned long long* bc = bc_scan + m * N_NODES;

    __shared__ __align__(16) unsigned short s_c16[N_NODES];   // 8 KB

    const int t = threadIdx.x;
    {
        uint2 v = ((const uint2*)cm)[t];
        *(uint2*)&s_c16[t * 4] = v;
    }
    __syncthreads();

    const int wave = t >> 6, lane = t & 63;
    const unsigned idx = blockIdx.x * 16 + wave;
    if (idx >= count) return;                   // wave-uniform
    const int r = (int)wlist[m * N_NODES + idx];
    const unsigned short ci16 = s_c16[r];

    const unsigned short* row = D + (size_t)r * N_NODES;
    unsigned* rtr = rt + (size_t)r * 64;
    unsigned tm = rtr[lane];
    unsigned long long bcv = bc[ci16];

    unsigned tmin = wave_min_u32(tm);
    if (bcv != KEY_INF && (tmin >> 12) > (unsigned)(bcv >> 24)) return;

    unsigned avail = tm;
    unsigned sel;
    sel = ((avail >> 12) << 6) | (unsigned)lane;
    sel = wave_min_u32(sel);
    const int t0 = (int)(sel & 63);
    if (lane == t0) avail = U32_INF;
    sel = ((avail >> 12) << 6) | (unsigned)lane;
    sel = wave_min_u32(sel);
    const int t1 = (int)(sel & 63);
    if (lane == t1) avail = U32_INF;
    sel = ((avail >> 12) << 6) | (unsigned)lane;
    sel = wave_min_u32(sel);
    const int t2 = (int)(sel & 63);
    if (lane == t2) avail = U32_INF;
    sel = ((avail >> 12) << 6) | (unsigned)lane;
    sel = wave_min_u32(sel);
    const int t3 = (int)(sel & 63);

    unsigned short dv0 = row[t0 * 64 + lane];
    unsigned short dv1 = row[t1 * 64 + lane];
    unsigned short dv2 = row[t2 * 64 + lane];
    unsigned short dv3 = row[t3 * 64 + lane];
    unsigned short cv0 = s_c16[t0 * 64 + lane];
    unsigned short cv1 = s_c16[t1 * 64 + lane];
    unsigned short cv2 = s_c16[t2 * 64 + lane];
    unsigned short cv3 = s_c16[t3 * 64 + lane];
    unsigned F0 = wave_min_u32((cv0 != ci16) ? (((unsigned)dv0 << 12) | (unsigned)(t0 * 64 + lane)) : U32_INF);
    unsigned F1 = wave_min_u32((cv1 != ci16) ? (((unsigned)dv1 << 12) | (unsigned)(t1 * 64 + lane)) : U32_INF);
    unsigned F2 = wave_min_u32((cv2 != ci16) ? (((unsigned)dv2 << 12) | (unsigned)(t2 * 64 + lane)) : U32_INF);
    unsigned F3 = wave_min_u32((cv3 != ci16) ? (((unsigned)dv3 << 12) | (unsigned)(t3 * 64 + lane)) : U32_INF);
    unsigned B = u32min(u32min(F0, F1), u32min(F2, F3));
    if (lane == 0) { rtr[t0] = F0; rtr[t1] = F1; rtr[t2] = F2; rtr[t3] = F3; }
    if (lane == t0) tm = F0;
    if (lane == t1) tm = F1;
    if (lane == t2) tm = F2;
    if (lane == t3) tm = F3;

    unsigned long long need = __ballot(tm < B);
    if (need) {
        if (__popcll(need) > 6) {
            unsigned best32 = B;
            const unsigned cirep = (unsigned)ci16 | ((unsigned)ci16 << 16);
            #pragma unroll 4
            for (int it = 0; it < 8; it++) {
                const int e0 = it * 512 + lane * 8;
                uint4 dvv = *(const uint4*)&row[e0];
                uint4 cvv = *(const uint4*)&s_c16[e0];
                unsigned px = cvv.x ^ cirep, py = cvv.y ^ cirep;
                unsigned pz = cvv.z ^ cirep, pw = cvv.w ^ cirep;
                if (px | py | pz | pw) {
                    unsigned dws[4] = {dvv.x, dvv.y, dvv.z, dvv.w};
                    unsigned pp[4] = {px, py, pz, pw};
                    #pragma unroll
                    for (int h = 0; h < 4; h++) {
                        unsigned j0 = (unsigned)(e0 + h * 2);
                        if (pp[h] & 0xFFFFu)
                            best32 = u32min(best32, ((dws[h] & 0xFFFFu) << 12) | j0);
                        if (pp[h] >> 16)
                            best32 = u32min(best32, ((dws[h] >> 16) << 12) | (j0 + 1));
                    }
                }
            }
            B = wave_min_u32(best32);
        } else {
            while (need) {
                const int tl = __ffsll((unsigned long long)need) - 1;
                need &= need - 1;
                unsigned bnd = (unsigned)__shfl((int)tm, tl);
                if (bnd >= B) continue;
                unsigned short dv = row[tl * 64 + lane];
                unsigned short cv = s_c16[tl * 64 + lane];
                unsigned f = wave_min_u32((cv != ci16)
                    ? (((unsigned)dv << 12) | (unsigned)(tl * 64 + lane)) : U32_INF);
                if (lane == 0) rtr[tl] = f;
                B = u32min(B, f);
            }
        }
    }

    unsigned long long cached;
    if (B != U32_INF) {
        unsigned j = B & 0xFFFu, d16 = B >> 12;
        unsigned a = (unsigned)r < j ? (unsigned)r : j;
        unsigned b2 = (unsigned)r < j ? j : (unsigned)r;
        cached = ((unsigned long long)d16 << 24) | ((unsigned long long)a << 12) | b2;
    } else {
        cached = KEY_INF;
    }
    if (lane == 0) {
        br[r] = cached;
        if (cached != KEY_INF) atomicMin(&bc[ci16], cached);
    }
}

// ---------------- persistent tail: SAFETY NET only (no-op when done) ---------
__device__ inline void tail_process_mask(unsigned long long mask, int rowbase,
                                         const unsigned short* __restrict__ D,
                                         unsigned* __restrict__ rt,
                                         unsigned short* s_c,
                                         unsigned long long* s_br,
                                         unsigned long long* s_bc,
                                         int lane) {
    while (mask) {
        const int l = __ffsll(mask) - 1; mask &= mask - 1;
        const int r = rowbase + l;
        const unsigned short ci16 = s_c[r];
        unsigned* rtr = rt + (size_t)r * 64;
        unsigned tm = rtr[lane];
        unsigned tmin = wave_min_u32(tm);
        unsigned long long bcv = s_bc[ci16];
        if (bcv != KEY_INF && (tmin >> 12) > (unsigned)(bcv >> 24)) continue;
        const unsigned short* row = D + (size_t)r * N_NODES;
        bool scanned = false;
        unsigned B = U32_INF;
        for (int it = 0; it < 64; ++it) {
            unsigned long long my =
                ((unsigned long long)(scanned ? U32_INF : tm) << 8) | (unsigned)lane;
            #pragma unroll
            for (int s = 32; s; s >>= 1) my = u64min(my, shfl_xor_u64(my, s));
            unsigned wtm = (unsigned)(my >> 8);
            if (wtm >= B) break;
            const int tl = (int)(my & 0xFFu);
            unsigned short dv = row[tl * 64 + lane];
            unsigned short cv = s_c[tl * 64 + lane];
            unsigned f = wave_min_u32((cv != ci16)
                ? (((unsigned)dv << 12) | (unsigned)(tl * 64 + lane)) : U32_INF);
            if (lane == tl) { scanned = true; tm = f; }
            if (lane == 0) rtr[tl] = f;
            B = u32min(B, f);
        }
        if (lane == 0) {
            if (B != U32_INF) {
                unsigned j = B & 0xFFFu, d16 = B >> 12;
                unsigned a = (unsigned)r < j ? (unsigned)r : j;
                unsigned b2 = (unsigned)r < j ? j : (unsigned)r;
                unsigned long long key = ((unsigned long long)d16 << 24) |
                    ((unsigned long long)a << 12) | b2;
                s_br[r] = key;
                atomicMin(&s_bc[ci16], key);
            } else {
                s_br[r] = KEY_INF;
            }
        }
    }
}

__global__ __launch_bounds__(1024) void boruvka_tail(const unsigned short* __restrict__ D0,
                                                     const unsigned short* __restrict__ D1,
                                                     unsigned short* __restrict__ comp16,
                                                     unsigned* __restrict__ rowtile,
                                                     unsigned long long* __restrict__ best_row,
                                                     float* __restrict__ deaths,
                                                     unsigned* __restrict__ cnt,
                                                     unsigned* __restrict__ done) {
    const int m = blockIdx.x;
    if (done[m]) return;
    const unsigned short* __restrict__ D = m ? D1 : D0;
    unsigned* rt = rowtile + (size_t)m * N_NODES * 64;
    float* dth = deaths + m * N_NODES;

    __shared__ unsigned short s_c[N_NODES];
    __shared__ unsigned short s_mp[N_NODES];
    __shared__ unsigned long long s_br[N_NODES];
    __shared__ unsigned long long s_bc[N_NODES];
    __shared__ unsigned s_cnt;

    const int t = threadIdx.x;
    const int wave = t >> 6, lane = t & 63;

    for (int i = t; i < N_NODES; i += 1024) {
        s_c[i] = comp16[m * N_NODES + i];
        s_br[i] = best_row[m * N_NODES + i];
        s_bc[i] = KEY_INF;
    }
    if (t == 0) s_cnt = cnt[m];
    __syncthreads();

    for (int round = 0; round < 16; ++round) {
        unsigned long long pend[4];
        #pragma unroll
        for (int b = 0; b < 4; b++) {
            const int rr = wave * 256 + b * 64 + lane;
            unsigned long long k = s_br[rr];
            bool need = false;
            if (k != KEY_INF) {
                unsigned canon = (unsigned)(k & 0xFFFFFFu);
                unsigned a = canon >> 12, bb = canon & 0xFFFu;
                unsigned j = (a == (unsigned)rr) ? bb : a;
                if (s_c[j] == s_c[rr]) need = true;
                else atomicMin(&s_bc[s_c[rr]], k);
            }
            pend[b] = __ballot(need);
            s_mp[rr] = (unsigned short)rr;
        }
        __syncthreads();

        #pragma unroll
        for (int b = 0; b < 4; b++)
            tail_process_mask(pend[b], wave * 256 + b * 64, D, rt, s_c, s_br, s_bc, lane);
        __syncthreads();

        for (int i = t; i < N_NODES; i += 1024) {
            unsigned long long k = s_bc[i];
            if (k != KEY_INF) {
                unsigned canon = (unsigned)(k & 0xFFFFFFu);
                unsigned a = canon >> 12, b = canon & 0xFFFu;
                unsigned ca = s_c[a], cb = s_c[b];
                unsigned other = (ca == (unsigned)i) ? cb : ca;
                s_mp[i] = (unsigned short)other;
                bool mutual = (s_bc[other] == k);
                if (!mutual || (unsigned)i < other) {
                    unsigned idx = atomicAdd(&s_cnt, 1u);
                    dth[idx] = half_bits_to_death((unsigned short)(k >> 24));
                }
            }
        }
        __syncthreads();

        unsigned nv[4];
        #pragma unroll
        for (int q = 0; q < 4; q++) {
            unsigned i = (unsigned)(t + q * 1024);
            unsigned p = s_mp[i], pp = s_mp[p];
            nv[q] = (pp == i) ? (i < p ? i : p) : p;
        }
        __syncthreads();
        #pragma unroll
        for (int q = 0; q < 4; q++) s_mp[t + q * 1024] = (unsigned short)nv[q];
        __syncthreads();
        #pragma unroll
        for (int q = 0; q < 4; q++) {
            unsigned rr = (unsigned)(t + q * 1024);
            unsigned p = s_mp[rr];
            while (p != rr) { rr = p; p = s_mp[rr]; }
            nv[q] = rr;
        }
        __syncthreads();
        #pragma unroll
        for (int q = 0; q < 4; q++) s_mp[t + q * 1024] = (unsigned short)nv[q];
        __syncthreads();

        for (int i = t; i < N_NODES; i += 1024) {
            s_c[i] = s_mp[s_c[i]];
            s_bc[i] = KEY_INF;
        }
        __syncthreads();
        if (s_cnt >= N_NODES - 1) break;
    }

    for (int i = t; i < N_NODES; i += 1024) {
        comp16[m * N_NODES + i] = s_c[i];
        best_row[m * N_NODES + i] = s_br[i];
    }
    if (t == 0) {
        cnt[m] = s_cnt;
        if (s_cnt >= N_NODES - 1) done[m] = 1u;
    }
}

// ---------------- sort (hybrid bitonic) + last-block finalize ----------------
__global__ __launch_bounds__(1024) void sortfinal_kernel(float* __restrict__ deaths,
                                                         const float* __restrict__ partials,
                                                         unsigned* __restrict__ sctl,
                                                         float* __restrict__ out) {
    float* d = deaths + blockIdx.x * N_NODES;
    __shared__ float s[N_NODES];
    __shared__ float red[16], red2[16];
    __shared__ int s_last;
    const int t = threadIdx.x;
    if (t == 0) s_last = 0;
    for (int i = t; i < N_NODES - 1; i += 1024) s[i] = d[i];
    if (t == 0) s[N_NODES - 1] = BIGF;
    __syncthreads();

    {
        float v[4];
        #pragma unroll
        for (int q = 0; q < 4; q++) v[q] = s[t + q * 1024];
        #pragma unroll
        for (int k = 2; k <= 32; k <<= 1) {
            for (int j = k >> 1; j; j >>= 1) {
                #pragma unroll
                for (int q = 0; q < 4; q++) {
                    float o = __shfl_xor(v[q], j);
                    bool up  = (t & j) == 0;
                    bool asc = (((t + q * 1024) & k) == 0);
                    float lo = fminf(v[q], o), hi = fmaxf(v[q], o);
                    v[q] = (asc == up) ? lo : hi;
                }
            }
        }
        #pragma unroll
        for (int q = 0; q < 4; q++) s[t + q * 1024] = v[q];
    }
    __syncthreads();

    for (int k = 64; k <= N_NODES; k <<= 1) {
        for (int j = k >> 1; j >= 64; j >>= 1) {
            #pragma unroll
            for (int q = 0; q < 4; q++) {
                int i = t + q * 1024;
                int p = i ^ j;
                if (p > i) {
                    float a = s[i], b = s[p];
                    bool asc = (i & k) == 0;
                    if ((a > b) == asc) { s[i] = b; s[p] = a; }
                }
            }
            __syncthreads();
        }
        float v[4];
        #pragma unroll
        for (int q = 0; q < 4; q++) v[q] = s[t + q * 1024];
        for (int j = 32; j; j >>= 1) {
            #pragma unroll
            for (int q = 0; q < 4; q++) {
                float o = __shfl_xor(v[q], j);
                bool up  = (t & j) == 0;
                bool asc = (((t + q * 1024) & k) == 0);
                float lo = fminf(v[q], o), hi = fmaxf(v[q], o);
                v[q] = (asc == up) ? lo : hi;
            }
        }
        #pragma unroll
        for (int q = 0; q < 4; q++) s[t + q * 1024] = v[q];
        __syncthreads();
    }
    for (int i = t; i < N_NODES - 1; i += 1024) d[i] = s[i];

    __threadfence();
    __syncthreads();
    if (t == 0) {
        unsigned old = atomicAdd(sctl, 1u);
        if (old == 1) s_last = 1;
    }
    __syncthreads();
    if (!s_last) return;
    __threadfence();

    float a = 0.f;
    for (int i = t; i < N_NODES - 1; i += 1024) {
        float x = __uint_as_float(atomicAdd((unsigned*)&deaths[i], 0u));
        float y = __uint_as_float(atomicAdd((unsigned*)&deaths[N_NODES + i], 0u));
        float dd = x - y;
        a += dd * dd;
    }
    float rsum = (t < 512) ? partials[t] : 0.f;
    #pragma unroll
    for (int off = 32; off; off >>= 1) { a += __shfl_xor(a, off); rsum += __shfl_xor(rsum, off); }
    if ((t & 63) == 0) { red[t >> 6] = a; red2[t >> 6] = rsum; }
    __syncthreads();
    if (t == 0) {
        float topo_sum = 0.f, repr_sum = 0.f;
        #pragma unroll
        for (int i = 0; i < 16; i++) { topo_sum += red[i]; repr_sum += red2[i]; }
        float repr = repr_sum / (float)(N_NODES * DIMS);
        float topo = topo_sum / (float)(2 * (N_NODES - 1));
        out[0] = 0.5f * repr + 0.5f * topo;
        out[1] = repr;
        out[2] = topo;
    }
}

// ---------------- host ----------------

extern "C" void kernel_launch(void* const* d_in, const int* in_sizes, int n_in,
                              void* d_out, int out_size, void* d_ws, size_t ws_size,
                              hipStream_t stream) {
    const float* S = (const float*)d_in[0];
    const float* T = (const float*)d_in[1];
    float* out = (float*)d_out;

    const size_t nn = (size_t)N_NODES * N_NODES;
    char* p = (char*)d_ws;
    __half* Ds = (__half*)p;                   p += nn * 2;
    __half* Dt = (__half*)p;                   p += nn * 2;
    unsigned short* X16s = (unsigned short*)p; p += (size_t)N_NODES * DIMS * 2;
    unsigned short* X16t = (unsigned short*)p; p += (size_t)N_NODES * DIMS * 2;
    unsigned long long* bcA = (unsigned long long*)p; p += (size_t)2 * N_NODES * 8;
    unsigned long long* bcB = (unsigned long long*)p; p += (size_t)2 * N_NODES * 8;
    unsigned long long* best_row = (unsigned long long*)p; p += 2 * N_NODES * 8;
    unsigned* rowtile  = (unsigned*)p; p += (size_t)2 * N_NODES * 64 * 4;
    float*    sqs      = (float*)p;    p += N_NODES * 4;
    float*    sqt      = (float*)p;    p += N_NODES * 4;
    float*    deaths   = (float*)p;    p += 2 * N_NODES * 4;
    float*    partials = (float*)p;    p += 512 * 4;
    unsigned short* cb0 = (unsigned short*)p; p += 2 * N_NODES * 2;
    unsigned short* cb1 = (unsigned short*)p; p += 2 * N_NODES * 2;
    unsigned short* wlist = (unsigned short*)p; p += 2 * N_NODES * 2;
    unsigned* wcount   = (unsigned*)p; p += 2 * 4;
    unsigned* cnt      = (unsigned*)p; p += 2 * 4;
    unsigned* done     = (unsigned*)p; p += 2 * 4;
    unsigned* sctl     = (unsigned*)p;

    unsigned long long* bcbuf[2] = { bcA, bcB };
    unsigned short* cbuf[2] = { cb0, cb1 };

    prep_kernel<<<N_NODES / 8, 256, 0, stream>>>(S, T, X16s, X16t, sqs, sqt, partials,
                                                 cb0, best_row, cnt, done, sctl);

    dim3 dg(N_NODES / 64, N_NODES / 64, 2);
    dist_kernel<<<dg, 256, 0, stream>>>(X16s, X16t, sqs, sqt, Ds, Dt, best_row, rowtile);

    // merge0: comps identity -> bc == best_row directly
    boruvka_merge2<<<2, 1024, 0, stream>>>(cb0, cb1, best_row, bcbuf[1], best_row,
                                           wlist, wcount, deaths, cnt, done);

    // 5 wide rounds (proven R19 config); tail is a near-no-op safety net.
    dim3 sg(N_NODES / 16, 2);
    for (int k = 1; k <= 5; k++) {
        boruvka_scanw<<<sg, 1024, 0, stream>>>((const unsigned short*)Ds,
                                               (const unsigned short*)Dt,
                                               cbuf[k & 1], wlist, wcount, rowtile,
                                               best_row, bcbuf[k & 1], done);
        boruvka_merge2<<<2, 1024, 0, stream>>>(cbuf[k & 1], cbuf[(k + 1) & 1],
                                               bcbuf[k & 1], bcbuf[(k + 1) & 1], best_row,
                                               wlist, wcount, deaths, cnt, done);
    }
    // after merge5, comps live in cbuf[0]
    boruvka_tail<<<2, 1024, 0, stream>>>((const unsigned short*)Ds,
                                         (const unsigned short*)Dt,
                                         cb0, rowtile, best_row, deaths, cnt, done);
    sortfinal_kernel<<<2, 1024, 0, stream>>>(deaths, partials, sctl, out);
}